// Round 11
// baseline (462.761 us; speedup 1.0000x reference)
//
#include <hip/hip_runtime.h>
#include <hip/hip_bf16.h>

// Problem constants (fixed by the harness)
#define NN  50000      // nodes
#define EE  800000     // edges before self-loops
#define NE2 850000     // edges + self-loops
#define NB  512        // graphs
#define NRT 3125       // row tiles of 16 (NN = 3125*16 exactly)
#define NSB 196        // scan blocks = ceil(NN/256)
#define NEB ((NE2 + 255) / 256)
// GAT1: F=128 -> 4 heads x 64 (256). GAT2: 256 -> 1 head x 128. GCN: 128 -> 64.

#define BN_RS 0.9999950000374997f   // 1/sqrt(1+1e-5)

typedef __attribute__((ext_vector_type(8))) short short8;
typedef __attribute__((ext_vector_type(4))) float f32x4;

__device__ __forceinline__ float bf2f(__hip_bfloat16 v) { return __bfloat162float(v); }
__device__ __forceinline__ unsigned short f2b(float v) {
    __hip_bfloat16 b = __float2bfloat16(v);
    return *reinterpret_cast<unsigned short*>(&b);
}
__device__ __forceinline__ float u2f(unsigned short u) {
    union { unsigned u; float f; } c; c.u = ((unsigned)u) << 16; return c.f;
}
__device__ __forceinline__ float lrelu01(float v) { return v > 0.f ? v : 0.01f * v; }
__device__ __forceinline__ float lrelu02(float v) { return v > 0.f ? v : 0.2f * v; }

// unpack 2 bf16 from a packed uint: low half = shift, high half = AND
__device__ __forceinline__ void up2(unsigned u, float& lo, float& hi) {
    union { unsigned x; float f; } a, b;
    a.x = u << 16; b.x = u & 0xFFFF0000u;
    lo = a.f; hi = b.f;
}
// acc[0..7] += e * bf16x8(u)
__device__ __forceinline__ void acc8(float* acc, uint4 u, float e) {
    float lo, hi;
    up2(u.x, lo, hi); acc[0] = fmaf(lo, e, acc[0]); acc[1] = fmaf(hi, e, acc[1]);
    up2(u.y, lo, hi); acc[2] = fmaf(lo, e, acc[2]); acc[3] = fmaf(hi, e, acc[3]);
    up2(u.z, lo, hi); acc[4] = fmaf(lo, e, acc[4]); acc[5] = fmaf(hi, e, acc[5]);
    up2(u.w, lo, hi); acc[6] = fmaf(lo, e, acc[6]); acc[7] = fmaf(hi, e, acc[7]);
}
__device__ __forceinline__ unsigned packbf2(float lo, float hi) {
    return ((unsigned)f2b(hi) << 16) | (unsigned)f2b(lo);
}

__device__ __forceinline__ void edge_sd(const int* __restrict__ ei, int e, int& s, int& d) {
    if (e < EE) { s = ei[e]; d = ei[EE + e]; }
    else        { s = e - EE; d = e - EE; }      // self-loop
}

__device__ __forceinline__ float ldf(const void* p, int i, bool bf) {
    return bf ? bf2f(((const __hip_bfloat16*)p)[i]) : ((const float*)p)[i];
}

#define NSEG 20
#define WTOT 85578
#define XQUADS (NN * 32)
// prep index space: EDGES FIRST (rank atomics overlap with convert work) | x quads |
// weights | W1t | W2t | Wgt
#define PREP_TOT (NE2 + XQUADS + WTOT + 32768 + 32768 + 8192)
struct SegArgs { const void* src[NSEG]; int off[NSEG]; };

// fused: per-block dtype detect + edge rank/degree + x->bf16 + fp32 weights + B^T transposes
__global__ __launch_bounds__(256) void prep_k(SegArgs a,
                                              const void* __restrict__ x_raw,
                                              ushort4* __restrict__ xb4,
                                              const void* __restrict__ W1r,
                                              const void* __restrict__ W2r,
                                              const void* __restrict__ Wgr,
                                              float* __restrict__ wf,
                                              unsigned short* __restrict__ W1t,
                                              unsigned short* __restrict__ W2t,
                                              unsigned short* __restrict__ Wgt,
                                              const int* __restrict__ ei,
                                              int* __restrict__ degi,
                                              int* __restrict__ rank,
                                              int* __restrict__ flag) {
    __shared__ int cnt;
    int t = threadIdx.x;
    if (t == 0) cnt = 0;
    __syncthreads();
    {
        int c = 0;
        const unsigned* xw = (const unsigned*)x_raw;
#pragma unroll
        for (int k = 0; k < 4; ++k) {
            unsigned w = xw[t * 4 + k];
            unsigned ef = (w >> 7) & 0xFFu;
            if (ef >= 100u && ef <= 140u) c++;
        }
        atomicAdd(&cnt, c);
    }
    __syncthreads();
    bool bf = (cnt > 512);
    if (blockIdx.x == 0 && t == 0) *flag = bf ? 1 : 0;

    int i = blockIdx.x * 256 + t;
    if (i >= PREP_TOT) return;
    if (i < NE2) {             // edge rank + degree count (degi pre-zeroed by memset)
        int s, d; edge_sd(ei, i, s, d);
        rank[i] = atomicAdd(&degi[d], 1);
        return;
    }
    i -= NE2;
    if (i < XQUADS) {
        ushort4 o;
        if (bf) o = ((const ushort4*)x_raw)[i];
        else {
            float4 v = ((const float4*)x_raw)[i];
            o.x = f2b(v.x); o.y = f2b(v.y); o.z = f2b(v.z); o.w = f2b(v.w);
        }
        xb4[i] = o;
        return;
    }
    i -= XQUADS;
    if (i < WTOT) {
        int s = 0;
#pragma unroll
        for (int k = 1; k < NSEG; ++k) if (i >= a.off[k]) s = k;
        wf[i] = ldf(a.src[s], i - a.off[s], bf);
        return;
    }
    i -= WTOT;
    if (i < 32768) {           // W1 [128][256] -> W1t[n*128+k]
        int n = i >> 7, k = i & 127;
        W1t[i] = f2b(ldf(W1r, k * 256 + n, bf));
        return;
    }
    i -= 32768;
    if (i < 32768) {           // W2 [256][128] -> W2t[n*256+k]
        int n = i >> 8, k = i & 255;
        W2t[i] = f2b(ldf(W2r, k * 128 + n, bf));
        return;
    }
    i -= 32768;
    {                          // Wg [128][64] -> Wgt[n*128+k]
        int n = i >> 7, k = i & 127;
        Wgt[i] = f2b(ldf(Wgr, k * 64 + n, bf));
    }
}

// ---------------- CSR scan phases ----------------
__global__ __launch_bounds__(256) void pscan_k(const int* __restrict__ degi,
                                               int* __restrict__ incl, int* __restrict__ bsum) {
    __shared__ int tmp[256];
    int t = threadIdx.x;
    int i = blockIdx.x * 256 + t;
    int v = (i < NN) ? degi[i] : 0;
    tmp[t] = v;
    __syncthreads();
#pragma unroll
    for (int off = 1; off < 256; off <<= 1) {
        int u = (t >= off) ? tmp[t - off] : 0;
        __syncthreads();
        tmp[t] += u;
        __syncthreads();
    }
    if (i < NN) incl[i] = tmp[t];
    if (t == 255) bsum[blockIdx.x] = tmp[255];
}

// phase 2: exclusive row_ptr + dis + graph bounds; folds the block-sum prefix
// (each block reduces bsum[t < blockIdx] itself -- replaces the bscan launch)
__global__ __launch_bounds__(256) void fscan_k(const int* __restrict__ degi,
                                               const int* __restrict__ incl,
                                               const int* __restrict__ bsum,
                                               const int* __restrict__ batch,
                                               int* __restrict__ row_ptr,
                                               float* __restrict__ dis, int* __restrict__ gstart) {
    __shared__ int tmp[256];
    int t = threadIdx.x, b = blockIdx.x;
    int i = b * 256 + t;
    int x = (t < NSB && t < b) ? bsum[t] : 0;
    tmp[t] = x;
    __syncthreads();
#pragma unroll
    for (int off = 128; off > 0; off >>= 1) {
        if (t < off) tmp[t] += tmp[t + off];
        __syncthreads();
    }
    int base = tmp[0];
    if (i <= NB) {
        int lo = 0, hi = NN;
        while (lo < hi) { int mid = (lo + hi) >> 1; if (batch[mid] < i) lo = mid + 1; else hi = mid; }
        gstart[i] = lo;
    }
    if (i >= NN) return;
    int dg = degi[i];
    int ex = base + incl[i] - dg;
    row_ptr[i] = ex;
    dis[i] = dg > 0 ? rsqrtf((float)dg) : 0.f;
    if (i == NN - 1) row_ptr[NN] = ex + dg;
}

// atomic-free scatter: pos = row_ptr[d] + rank[e] (rank computed in prep_k)
__global__ __launch_bounds__(256) void scatter_k(const int* __restrict__ ei,
                                                 const int* __restrict__ row_ptr,
                                                 const int* __restrict__ rank,
                                                 int* __restrict__ csr_src) {
    int e = blockIdx.x * 256 + threadIdx.x;
    if (e >= NE2) return;
    int s, d; edge_sd(ei, e, s, d);
    csr_src[row_ptr[d] + rank[e]] = s;
}

// ---------------- GEMM1 + fused GAT1 scores: 4 row-tiles/block, B held in regs --------
__global__ __launch_bounds__(256) void mgemm1_k(const short* __restrict__ A,    // xb [N][128]
                                                const short* __restrict__ Bt,   // W1t [256][128]
                                                unsigned short* __restrict__ C, // h1b [N][256]
                                                const float* __restrict__ a_s,  // [256]
                                                const float* __restrict__ a_d,
                                                float* __restrict__ sc_s,       // [N*4]
                                                float* __restrict__ sc_d) {
    int wave = threadIdx.x >> 6, lane = threadIdx.x & 63;
    int cg = wave;
    int l15 = lane & 15, quad = lane >> 4;
    const short* bp = Bt + (size_t)(cg * 64 + l15) * 128 + quad * 8;
    short8 bfr[4][4];
#pragma unroll
    for (int j = 0; j < 4; ++j)
#pragma unroll
        for (int kk = 0; kk < 4; ++kk)
            bfr[j][kk] = *(const short8*)(bp + (size_t)j * 16 * 128 + kk * 32);
    float asv[4], adv[4];
#pragma unroll
    for (int j = 0; j < 4; ++j) {
        asv[j] = a_s[cg * 64 + j * 16 + l15];
        adv[j] = a_d[cg * 64 + j * 16 + l15];
    }
#pragma unroll
    for (int rtl = 0; rtl < 4; ++rtl) {
        int rt = blockIdx.x * 4 + rtl;
        if (rt >= NRT) break;
        const short* ap = A + (size_t)(rt * 16 + l15) * 128 + quad * 8;
        f32x4 acc[4] = {};
#pragma unroll
        for (int kk = 0; kk < 4; ++kk) {
            short8 a = *(const short8*)(ap + kk * 32);
#pragma unroll
            for (int j = 0; j < 4; ++j)
                acc[j] = __builtin_amdgcn_mfma_f32_16x16x32_bf16(a, bfr[j][kk], acc[j], 0, 0, 0);
        }
        float ss[4] = {0.f, 0.f, 0.f, 0.f}, sd[4] = {0.f, 0.f, 0.f, 0.f};
#pragma unroll
        for (int j = 0; j < 4; ++j) {
            int n = cg * 64 + j * 16 + l15;
#pragma unroll
            for (int r = 0; r < 4; ++r) {
                float v = acc[j][r];
                C[(size_t)(rt * 16 + quad * 4 + r) * 256 + n] = f2b(v);
                ss[r] = fmaf(v, asv[j], ss[r]);
                sd[r] = fmaf(v, adv[j], sd[r]);
            }
        }
#pragma unroll
        for (int off = 1; off < 16; off <<= 1) {
#pragma unroll
            for (int r = 0; r < 4; ++r) {
                ss[r] += __shfl_xor(ss[r], off);
                sd[r] += __shfl_xor(sd[r], off);
            }
        }
        if (l15 == 0) {
#pragma unroll
            for (int r = 0; r < 4; ++r) {
                int node = rt * 16 + quad * 4 + r;
                sc_s[node * 4 + cg] = ss[r];
                sc_d[node * 4 + cg] = sd[r];
            }
        }
    }
}

// ---------------- GEMM2 + fused GAT2 scores ----------------
__global__ __launch_bounds__(256) void mgemm2_k(const short* __restrict__ A,    // x1b [N][256]
                                                const short* __restrict__ Bt,   // W2t [128][256]
                                                unsigned short* __restrict__ C, // h2b [N][128]
                                                const float* __restrict__ a_s,  // [128]
                                                const float* __restrict__ a_d,
                                                float* __restrict__ sc_s,       // [N]
                                                float* __restrict__ sc_d) {
    __shared__ float sred[4][16][2];
    int wave = threadIdx.x >> 6, lane = threadIdx.x & 63;
    int gidx = blockIdx.x * 4 + wave;
    bool act = gidx < NRT * 2;
    int gcl = act ? gidx : NRT * 2 - 1;
    int rt = gcl >> 1, cg = gcl & 1;
    int l15 = lane & 15, quad = lane >> 4;
    const short* ap = A + (size_t)(rt * 16 + l15) * 256 + quad * 8;
    const short* bp = Bt + (size_t)(cg * 64 + l15) * 256 + quad * 8;
    f32x4 acc[4] = {};
    for (int k0 = 0; k0 < 256; k0 += 32) {
        short8 a = *(const short8*)(ap + k0);
#pragma unroll
        for (int j = 0; j < 4; ++j) {
            short8 b = *(const short8*)(bp + (size_t)j * 16 * 256 + k0);
            acc[j] = __builtin_amdgcn_mfma_f32_16x16x32_bf16(a, b, acc[j], 0, 0, 0);
        }
    }
    float asv[4], adv[4];
#pragma unroll
    for (int j = 0; j < 4; ++j) {
        asv[j] = a_s[cg * 64 + j * 16 + l15];
        adv[j] = a_d[cg * 64 + j * 16 + l15];
    }
    float ss[4] = {0.f, 0.f, 0.f, 0.f}, sd[4] = {0.f, 0.f, 0.f, 0.f};
#pragma unroll
    for (int j = 0; j < 4; ++j) {
        int n = cg * 64 + j * 16 + l15;
#pragma unroll
        for (int r = 0; r < 4; ++r) {
            float v = acc[j][r];
            if (act) C[(size_t)(rt * 16 + quad * 4 + r) * 128 + n] = f2b(v);
            ss[r] = fmaf(v, asv[j], ss[r]);
            sd[r] = fmaf(v, adv[j], sd[r]);
        }
    }
#pragma unroll
    for (int off = 1; off < 16; off <<= 1) {
#pragma unroll
        for (int r = 0; r < 4; ++r) {
            ss[r] += __shfl_xor(ss[r], off);
            sd[r] += __shfl_xor(sd[r], off);
        }
    }
    if (l15 == 0) {
#pragma unroll
        for (int r = 0; r < 4; ++r) {
            sred[wave][quad * 4 + r][0] = ss[r];
            sred[wave][quad * 4 + r][1] = sd[r];
        }
    }
    __syncthreads();
    if (threadIdx.x < 32) {
        int rl = threadIdx.x >> 4, row = threadIdx.x & 15;
        int g2 = blockIdx.x * 4 + rl * 2;
        if (g2 < NRT * 2) {
            int node = (g2 >> 1) * 16 + row;
            sc_s[node] = sred[rl * 2][row][0] + sred[rl * 2 + 1][row][0];
            sc_d[node] = sred[rl * 2][row][1] + sred[rl * 2 + 1][row][1];
        }
    }
}

__device__ __forceinline__ float sel4(float4 v, int head) {
    float ab = (head & 1) ? v.y : v.x;
    float cd = (head & 1) ? v.w : v.z;
    return (head & 2) ? cd : ab;
}

// ---------------- GAT1 aggregate: wave/node, 4B L2 score gathers, masked tail ----------
__global__ __launch_bounds__(256) void agg1_k(const int* __restrict__ row_ptr,
                                              const int* __restrict__ csr_src,
                                              const uint4* __restrict__ h1b,    // [N*32]
                                              const float* __restrict__ sc_s,   // [N*4]
                                              const float4* __restrict__ sc_d4, // [N]
                                              const float4* __restrict__ b1,    // [64]
                                              const float4* __restrict__ g1,
                                              const float4* __restrict__ bb1,
                                              uint4* __restrict__ x1b) {
    int n = __builtin_amdgcn_readfirstlane((blockIdx.x * 256 + threadIdx.x) >> 6);
    int lane = threadIdx.x & 63;
    if (n >= NN) return;
    int g = lane >> 5, sl = lane & 31;
    int head = sl >> 3;
    int row = row_ptr[n], end = row_ptr[n + 1];
    float scd_h = sel4(sc_d4[n], head);
    float acc[8] = {0.f, 0.f, 0.f, 0.f, 0.f, 0.f, 0.f, 0.f};
    float den = 0.f;
    int c = row;
    for (; c + 7 < end; c += 8) {
        int i0 = c + g, i1 = c + 2 + g, i2 = c + 4 + g, i3 = c + 6 + g;
        int s0 = csr_src[i0], s1 = csr_src[i1], s2 = csr_src[i2], s3 = csr_src[i3];
        float w0 = sc_s[s0 * 4 + head], w1 = sc_s[s1 * 4 + head];
        float w2 = sc_s[s2 * 4 + head], w3 = sc_s[s3 * 4 + head];
        uint4 u0 = h1b[(size_t)s0 * 32 + sl];
        uint4 u1 = h1b[(size_t)s1 * 32 + sl];
        uint4 u2 = h1b[(size_t)s2 * 32 + sl];
        uint4 u3 = h1b[(size_t)s3 * 32 + sl];
        float e0 = __expf(lrelu02(w0 + scd_h));
        float e1 = __expf(lrelu02(w1 + scd_h));
        float e2 = __expf(lrelu02(w2 + scd_h));
        float e3 = __expf(lrelu02(w3 + scd_h));
        den += (e0 + e1) + (e2 + e3);
        acc8(acc, u0, e0); acc8(acc, u1, e1); acc8(acc, u2, e2); acc8(acc, u3, e3);
    }
    if (c < end) {                               // masked full-width tail (<=7 edges)
        int i0 = c + g, i1 = c + 2 + g, i2 = c + 4 + g, i3 = c + 6 + g;
        bool v0 = i0 < end, v1 = i1 < end, v2 = i2 < end, v3 = i3 < end;
        int l = end - 1;
        int s0 = csr_src[v0 ? i0 : l], s1 = csr_src[v1 ? i1 : l];
        int s2 = csr_src[v2 ? i2 : l], s3 = csr_src[v3 ? i3 : l];
        float w0 = sc_s[s0 * 4 + head], w1 = sc_s[s1 * 4 + head];
        float w2 = sc_s[s2 * 4 + head], w3 = sc_s[s3 * 4 + head];
        uint4 u0 = h1b[(size_t)s0 * 32 + sl];
        uint4 u1 = h1b[(size_t)s1 * 32 + sl];
        uint4 u2 = h1b[(size_t)s2 * 32 + sl];
        uint4 u3 = h1b[(size_t)s3 * 32 + sl];
        float e0 = v0 ? __expf(lrelu02(w0 + scd_h)) : 0.f;
        float e1 = v1 ? __expf(lrelu02(w1 + scd_h)) : 0.f;
        float e2 = v2 ? __expf(lrelu02(w2 + scd_h)) : 0.f;
        float e3 = v3 ? __expf(lrelu02(w3 + scd_h)) : 0.f;
        den += (e0 + e1) + (e2 + e3);
        acc8(acc, u0, e0); acc8(acc, u1, e1); acc8(acc, u2, e2); acc8(acc, u3, e3);
    }
    den += __shfl_xor(den, 32);
#pragma unroll
    for (int k = 0; k < 8; ++k) acc[k] += __shfl_xor(acc[k], 32);
    if (g == 0) {
        float inv = 1.f / (den + 1e-16f);
        float4 bA = b1[sl * 2],  bB = b1[sl * 2 + 1];
        float4 gA = g1[sl * 2],  gB = g1[sl * 2 + 1];
        float4 eA = bb1[sl * 2], eB = bb1[sl * 2 + 1];
        float o0 = lrelu01(fmaf(acc[0], inv, bA.x)) * (gA.x * BN_RS) + eA.x;
        float o1 = lrelu01(fmaf(acc[1], inv, bA.y)) * (gA.y * BN_RS) + eA.y;
        float o2 = lrelu01(fmaf(acc[2], inv, bA.z)) * (gA.z * BN_RS) + eA.z;
        float o3 = lrelu01(fmaf(acc[3], inv, bA.w)) * (gA.w * BN_RS) + eA.w;
        float o4 = lrelu01(fmaf(acc[4], inv, bB.x)) * (gB.x * BN_RS) + eB.x;
        float o5 = lrelu01(fmaf(acc[5], inv, bB.y)) * (gB.y * BN_RS) + eB.y;
        float o6 = lrelu01(fmaf(acc[6], inv, bB.z)) * (gB.z * BN_RS) + eB.z;
        float o7 = lrelu01(fmaf(acc[7], inv, bB.w)) * (gB.w * BN_RS) + eB.w;
        uint4 w;
        w.x = packbf2(o0, o1); w.y = packbf2(o2, o3);
        w.z = packbf2(o4, o5); w.w = packbf2(o6, o7);
        x1b[(size_t)n * 32 + sl] = w;
    }
}

// ---------------- GAT2 aggregate + fused GCN projection ------------------------------
// 4 edge-groups x 16 lanes gather h2b; after reduce, lanes 0-15 hold the full x2 row
// (bn2+lrelu applied, f32). Row staged in LDS, then all 64 lanes project one output
// feature each through Wgt (L2-hot 16KB) -> writes hgb directly. mgemm3 eliminated;
// x2b never materialized (saves 25.6MB of traffic + one launch).
__global__ __launch_bounds__(256) void agg2_k(const int* __restrict__ row_ptr,
                                              const int* __restrict__ csr_src,
                                              const uint4* __restrict__ h2b,   // [N*16]
                                              const float* __restrict__ sc_s,  // [N]
                                              const float* __restrict__ sc_d,
                                              const float4* __restrict__ b2,   // [32]
                                              const float4* __restrict__ g2,
                                              const float4* __restrict__ bb2,
                                              const uint4* __restrict__ Wgt4,  // [64][16] (bf16 rows)
                                              unsigned short* __restrict__ hgb) { // [N*64] bf16
    __shared__ float xsh[4][128];
    int wave = threadIdx.x >> 6;
    int n = __builtin_amdgcn_readfirstlane((blockIdx.x * 256 + threadIdx.x) >> 6);
    int lane = threadIdx.x & 63;
    // grid = exactly NN waves -> no early exit; __syncthreads below is safe
    int g = lane >> 4, sl = lane & 15;
    int row = row_ptr[n], end = row_ptr[n + 1];
    float scd = sc_d[n];
    float acc[8] = {0.f, 0.f, 0.f, 0.f, 0.f, 0.f, 0.f, 0.f};
    float den = 0.f;
    int c = row;
    for (; c + 15 < end; c += 16) {              // 4 slots/group, 16 edges/wave
        int i0 = c + g, i1 = c + 4 + g, i2 = c + 8 + g, i3 = c + 12 + g;
        int s0 = csr_src[i0], s1 = csr_src[i1], s2 = csr_src[i2], s3 = csr_src[i3];
        float c0 = sc_s[s0], c1 = sc_s[s1], c2 = sc_s[s2], c3 = sc_s[s3];
        uint4 u0 = h2b[(size_t)s0 * 16 + sl];
        uint4 u1 = h2b[(size_t)s1 * 16 + sl];
        uint4 u2 = h2b[(size_t)s2 * 16 + sl];
        uint4 u3 = h2b[(size_t)s3 * 16 + sl];
        float e0 = __expf(lrelu02(c0 + scd));
        float e1 = __expf(lrelu02(c1 + scd));
        float e2 = __expf(lrelu02(c2 + scd));
        float e3 = __expf(lrelu02(c3 + scd));
        den += (e0 + e1) + (e2 + e3);
        acc8(acc, u0, e0); acc8(acc, u1, e1); acc8(acc, u2, e2); acc8(acc, u3, e3);
    }
    if (c < end) {                               // masked full-width tail (<=15 edges)
        int i0 = c + g, i1 = c + 4 + g, i2 = c + 8 + g, i3 = c + 12 + g;
        bool v0 = i0 < end, v1 = i1 < end, v2 = i2 < end, v3 = i3 < end;
        int l = end - 1;
        int s0 = csr_src[v0 ? i0 : l], s1 = csr_src[v1 ? i1 : l];
        int s2 = csr_src[v2 ? i2 : l], s3 = csr_src[v3 ? i3 : l];
        float c0 = sc_s[s0], c1 = sc_s[s1], c2 = sc_s[s2], c3 = sc_s[s3];
        uint4 u0 = h2b[(size_t)s0 * 16 + sl];
        uint4 u1 = h2b[(size_t)s1 * 16 + sl];
        uint4 u2 = h2b[(size_t)s2 * 16 + sl];
        uint4 u3 = h2b[(size_t)s3 * 16 + sl];
        float e0 = v0 ? __expf(lrelu02(c0 + scd)) : 0.f;
        float e1 = v1 ? __expf(lrelu02(c1 + scd)) : 0.f;
        float e2 = v2 ? __expf(lrelu02(c2 + scd)) : 0.f;
        float e3 = v3 ? __expf(lrelu02(c3 + scd)) : 0.f;
        den += (e0 + e1) + (e2 + e3);
        acc8(acc, u0, e0); acc8(acc, u1, e1); acc8(acc, u2, e2); acc8(acc, u3, e3);
    }
    den += __shfl_xor(den, 16);
    den += __shfl_xor(den, 32);
#pragma unroll
    for (int k = 0; k < 8; ++k) {
        acc[k] += __shfl_xor(acc[k], 16);
        acc[k] += __shfl_xor(acc[k], 32);
    }
    if (lane < 16) {
        float inv = 1.f / (den + 1e-16f);
        float4 bA = b2[sl * 2],  bB = b2[sl * 2 + 1];
        float4 gA = g2[sl * 2],  gB = g2[sl * 2 + 1];
        float4 eA = bb2[sl * 2], eB = bb2[sl * 2 + 1];
        xsh[wave][sl * 8 + 0] = lrelu01(fmaf(acc[0], inv, bA.x)) * (gA.x * BN_RS) + eA.x;
        xsh[wave][sl * 8 + 1] = lrelu01(fmaf(acc[1], inv, bA.y)) * (gA.y * BN_RS) + eA.y;
        xsh[wave][sl * 8 + 2] = lrelu01(fmaf(acc[2], inv, bA.z)) * (gA.z * BN_RS) + eA.z;
        xsh[wave][sl * 8 + 3] = lrelu01(fmaf(acc[3], inv, bA.w)) * (gA.w * BN_RS) + eA.w;
        xsh[wave][sl * 8 + 4] = lrelu01(fmaf(acc[4], inv, bB.x)) * (gB.x * BN_RS) + eB.x;
        xsh[wave][sl * 8 + 5] = lrelu01(fmaf(acc[5], inv, bB.y)) * (gB.y * BN_RS) + eB.y;
        xsh[wave][sl * 8 + 6] = lrelu01(fmaf(acc[6], inv, bB.z)) * (gB.z * BN_RS) + eB.z;
        xsh[wave][sl * 8 + 7] = lrelu01(fmaf(acc[7], inv, bB.w)) * (gB.w * BN_RS) + eB.w;
    }
    __syncthreads();
    // GCN projection: lane f' computes hg[n][f'] = sum_k x2[k] * Wg[k][f']
    float hacc = 0.f;
    const float* xr = xsh[wave];
#pragma unroll
    for (int kk = 0; kk < 16; ++kk) {
        uint4 wv = Wgt4[lane * 16 + kk];
        int kb = kk * 8;
        float lo, hi;
        up2(wv.x, lo, hi); hacc = fmaf(xr[kb + 0], lo, hacc); hacc = fmaf(xr[kb + 1], hi, hacc);
        up2(wv.y, lo, hi); hacc = fmaf(xr[kb + 2], lo, hacc); hacc = fmaf(xr[kb + 3], hi, hacc);
        up2(wv.z, lo, hi); hacc = fmaf(xr[kb + 4], lo, hacc); hacc = fmaf(xr[kb + 5], hi, hacc);
        up2(wv.w, lo, hi); hacc = fmaf(xr[kb + 6], lo, hacc); hacc = fmaf(xr[kb + 7], hi, hacc);
    }
    hgb[(size_t)n * 64 + lane] = f2b(hacc);
}

// ---------------- GCN aggregate: 8 edge-groups x 8 lanes, masked tail; bf16 x3 ---------
__global__ __launch_bounds__(256) void gcn_k(const int* __restrict__ row_ptr,
                                             const int* __restrict__ csr_src,
                                             const uint4* __restrict__ hgb,  // [N*8]
                                             const float* __restrict__ dis,
                                             const float4* __restrict__ bg,  // [16]
                                             uint4* __restrict__ x3b) {      // [N*8] bf16
    int n = __builtin_amdgcn_readfirstlane((blockIdx.x * 256 + threadIdx.x) >> 6);
    int lane = threadIdx.x & 63;
    if (n >= NN) return;
    int g = lane >> 3, sl = lane & 7;
    int row = row_ptr[n], end = row_ptr[n + 1];
    float dn = dis[n];
    float acc[8] = {0.f, 0.f, 0.f, 0.f, 0.f, 0.f, 0.f, 0.f};
    int c = row;
    for (; c + 15 < end; c += 16) {              // 2 slots/group, 16 edges/wave
        int i0 = c + g, i1 = c + 8 + g;
        int s0 = csr_src[i0], s1 = csr_src[i1];
        float w0 = dis[s0], w1 = dis[s1];
        uint4 u0 = hgb[(size_t)s0 * 8 + sl];
        uint4 u1 = hgb[(size_t)s1 * 8 + sl];
        acc8(acc, u0, w0); acc8(acc, u1, w1);
    }
    if (c < end) {                               // masked full-width tail (<=15 edges)
        int i0 = c + g, i1 = c + 8 + g;
        bool v0 = i0 < end, v1 = i1 < end;
        int l = end - 1;
        int s0 = csr_src[v0 ? i0 : l], s1 = csr_src[v1 ? i1 : l];
        float w0 = v0 ? dis[s0] : 0.f, w1 = v1 ? dis[s1] : 0.f;
        uint4 u0 = hgb[(size_t)s0 * 8 + sl];
        uint4 u1 = hgb[(size_t)s1 * 8 + sl];
        acc8(acc, u0, w0); acc8(acc, u1, w1);
    }
#pragma unroll
    for (int off = 8; off <= 32; off <<= 1) {
#pragma unroll
        for (int k = 0; k < 8; ++k) acc[k] += __shfl_xor(acc[k], off);
    }
    if (lane < 8) {
        float4 bA = bg[sl * 2], bB = bg[sl * 2 + 1];
        float o0 = lrelu01(fmaf(acc[0], dn, bA.x));
        float o1 = lrelu01(fmaf(acc[1], dn, bA.y));
        float o2 = lrelu01(fmaf(acc[2], dn, bA.z));
        float o3 = lrelu01(fmaf(acc[3], dn, bA.w));
        float o4 = lrelu01(fmaf(acc[4], dn, bB.x));
        float o5 = lrelu01(fmaf(acc[5], dn, bB.y));
        float o6 = lrelu01(fmaf(acc[6], dn, bB.z));
        float o7 = lrelu01(fmaf(acc[7], dn, bB.w));
        uint4 w;
        w.x = packbf2(o0, o1); w.y = packbf2(o2, o3);
        w.z = packbf2(o4, o5); w.w = packbf2(o6, o7);
        x3b[(size_t)n * 8 + sl] = w;
    }
}

// ---------------- fused mean-pool + MLP head: block per graph (bf16 x3) ----------------
__global__ __launch_bounds__(256) void poolmlp_k(const unsigned short* __restrict__ x3b,
                                                 const int* __restrict__ gstart,
                                                 const float* __restrict__ l1W,
                                                 const float* __restrict__ l1b,
                                                 const float* __restrict__ g3,
                                                 const float* __restrict__ b3,
                                                 const float* __restrict__ l2W,
                                                 const float* __restrict__ l2b,
                                                 void* __restrict__ outp,
                                                 const int* __restrict__ flag) {
    __shared__ float red[4][64];
    __shared__ float pl[64];
    __shared__ float y1s[128];
    int g = blockIdx.x, t = threadIdx.x;
    int c = t & 63, r = t >> 6;
    int s = gstart[g], e = gstart[g + 1];
    float sum = 0.f;
    for (int n = s + r; n < e; n += 4) sum += u2f(x3b[(size_t)n * 64 + c]);
    red[r][c] = sum;
    __syncthreads();
    if (t < 64) {
        float v = red[0][t] + red[1][t] + red[2][t] + red[3][t];
        int cnt = e - s; if (cnt < 1) cnt = 1;
        pl[t] = v / (float)cnt;
    }
    __syncthreads();
    if (t < 128) {
        float acc = l1b[t];
#pragma unroll 8
        for (int j = 0; j < 64; ++j) acc = fmaf(pl[j], l1W[j * 128 + t], acc);
        acc = acc * (g3[t] * BN_RS) + b3[t];
        y1s[t] = lrelu01(acc);
    }
    __syncthreads();
    if (t < 10) {
        float o = l2b[t];
#pragma unroll 8
        for (int j = 0; j < 128; ++j) o = fmaf(y1s[j], l2W[j * 10 + t], o);
        if (*flag) ((__hip_bfloat16*)outp)[g * 10 + t] = __float2bfloat16(o);
        else       ((float*)outp)[g * 10 + t] = o;
    }
}

// weight segment sizes (W1,as1,ad1,b1,W2,as2,ad2,b2,Wg,bg,bn1g,bn1b,bn2g,bn2b,bn3g,bn3b,l1W,l1b,l2W,l2b)
static const int kSegN[NSEG]  = {32768, 256, 256, 256, 32768, 128, 128, 128, 8192, 64,
                                 256, 256, 128, 128, 128, 128, 8192, 128, 1280, 10};
static const int kSegIn[NSEG] = {3, 4, 5, 6, 7, 8, 9, 10, 11, 12, 13, 14, 15, 16, 17, 18, 19, 20, 21, 22};

extern "C" void kernel_launch(void* const* d_in, const int* in_sizes, int n_in,
                              void* d_out, int out_size, void* d_ws, size_t ws_size,
                              hipStream_t stream) {
    const void* x_raw = d_in[0];
    const int*  ei    = (const int*)d_in[1];
    const int*  batch = (const int*)d_in[2];

    // ---- workspace layout ----
    int*   flag = (int*)d_ws;
    float* ws   = (float*)d_ws;
    unsigned short* xb = (unsigned short*)(ws + 16);          // N*128 bf16
    float* wf   = ws + 16 + (size_t)NN * 64;                  // 85584 fp32 canonical
    unsigned short* W1t = (unsigned short*)(wf + 85584);      // 32768 bf16 [256][128]
    unsigned short* W2t = W1t + 32768;                        // 32768 bf16 [128][256]
    unsigned short* Wgt = W2t + 32768;                        // 8192  bf16 [64][128]
    unsigned short* h1b = Wgt + 8192;                         // N*256 bf16 (reused as h2b)
    unsigned short* x1b = h1b + (size_t)NN * 256;             // N*256 bf16
    unsigned short* hgb = x1b + (size_t)NN * 256;             // N*64 bf16
    unsigned short* x3b = hgb + (size_t)NN * 64;              // N*64 bf16
    float* sc_s1 = (float*)(x3b + (size_t)NN * 64);           // N*4
    float* sc_d1 = sc_s1 + (size_t)NN * 4;                    // N*4
    float* sc_s2 = sc_d1 + (size_t)NN * 4;                    // N
    float* sc_d2 = sc_s2 + NN;                                // N
    float* disb  = sc_d2 + NN;                                // N
    int*   gstart = (int*)(disb + NN);                        // B+1
    int*   degi   = gstart + NB + 4;                          // N
    int*   incl   = degi + NN;                                // N
    int*   bsum   = incl + NN;                                // 256
    int*   row_ptr = bsum + 256;                              // N+1
    int*   csr_src = row_ptr + NN + 4;                        // NE2

    // rank[e]: within-destination edge rank, produced by prep_k, consumed by scatter_k.
    // Aliases x1b region (first written by agg1_k, which runs after scatter_k).
    int*   rankb = (int*)x1b;                                 // NE2 ints (3.4MB of 25.6MB)

    int off[NSEG]; int o = 0;
    for (int s = 0; s < NSEG; ++s) { off[s] = o; o += kSegN[s]; }
    float* as1f = wf + off[1];  float* ad1f = wf + off[2];
    float* b1f  = wf + off[3];  float* as2f = wf + off[5];
    float* ad2f = wf + off[6];  float* b2f  = wf + off[7];
    float* bgf  = wf + off[9];  float* bn1g = wf + off[10]; float* bn1b = wf + off[11];
    float* bn2g = wf + off[12]; float* bn2b = wf + off[13]; float* bn3g = wf + off[14];
    float* bn3b = wf + off[15]; float* l1Wf = wf + off[16]; float* l1bf = wf + off[17];
    float* l2Wf = wf + off[18]; float* l2bf = wf + off[19];

    unsigned short* h2b = h1b;   // h1b dead after agg1_k

    // ---- prep: degi zero (memset) + edge rank + detect/convert/transpose (one kernel) ----
    hipMemsetAsync(degi, 0, NN * sizeof(int), stream);
    SegArgs sa;
    for (int s = 0; s < NSEG; ++s) { sa.src[s] = d_in[kSegIn[s]]; sa.off[s] = off[s]; }
    prep_k<<<(PREP_TOT + 255) / 256, 256, 0, stream>>>(sa, x_raw, (ushort4*)xb,
                                                       d_in[3], d_in[7], d_in[11],
                                                       wf, W1t, W2t, Wgt, ei, degi, rankb, flag);

    // ---- CSR build (by destination) + graph bounds; bscan folded into fscan ----
    pscan_k<<<NSB, 256, 0, stream>>>(degi, incl, bsum);
    fscan_k<<<NSB, 256, 0, stream>>>(degi, incl, bsum, batch, row_ptr, disb, gstart);
    scatter_k<<<NEB, 256, 0, stream>>>(ei, row_ptr, rankb, csr_src);

    // ---- GAT layer 1 (scores fused into GEMM; 4B L2 score gathers in aggregate) ----
    mgemm1_k<<<(NRT + 3) / 4, 256, 0, stream>>>((const short*)xb, (const short*)W1t, h1b,
                                                as1f, ad1f, sc_s1, sc_d1);
    agg1_k<<<12500, 256, 0, stream>>>(row_ptr, csr_src, (const uint4*)h1b,
                                      sc_s1, (const float4*)sc_d1,
                                      (const float4*)b1f, (const float4*)bn1g,
                                      (const float4*)bn1b, (uint4*)x1b);

    // ---- GAT layer 2 + fused GCN projection (mgemm3 eliminated) ----
    mgemm2_k<<<(NRT * 2 + 3) / 4, 256, 0, stream>>>((const short*)x1b, (const short*)W2t, h2b,
                                                    as2f, ad2f, sc_s2, sc_d2);
    agg2_k<<<12500, 256, 0, stream>>>(row_ptr, csr_src, (const uint4*)h2b,
                                      sc_s2, sc_d2,
                                      (const float4*)b2f, (const float4*)bn2g,
                                      (const float4*)bn2b, (const uint4*)Wgt, hgb);

    // ---- GCN aggregate + fused pool/MLP ----
    gcn_k<<<12500, 256, 0, stream>>>(row_ptr, csr_src, (const uint4*)hgb, disb,
                                     (const float4*)bgf, (uint4*)x3b);
    poolmlp_k<<<NB, 256, 0, stream>>>(x3b, gstart, l1Wf, l1bf, bn3g, bn3b, l2Wf, l2bf,
                                      d_out, flag);
}

// Round 12
// 381.887 us; speedup vs baseline: 1.2118x; 1.2118x over previous
//
#include <hip/hip_runtime.h>
#include <hip/hip_bf16.h>

// Problem constants (fixed by the harness)
#define NN  50000      // nodes
#define EE  800000     // edges before self-loops
#define NE2 850000     // edges + self-loops
#define NB  512        // graphs
#define NRT 3125       // row tiles of 16 (NN = 3125*16 exactly)
#define NSB 196        // scan blocks = ceil(NN/256)
#define NEB ((NE2 + 255) / 256)
// GAT1: F=128 -> 4 heads x 64 (256). GAT2: 256 -> 1 head x 128. GCN: 128 -> 64.

#define BN_RS 0.9999950000374997f   // 1/sqrt(1+1e-5)

typedef __attribute__((ext_vector_type(8))) short short8;
typedef __attribute__((ext_vector_type(4))) float f32x4;

__device__ __forceinline__ float bf2f(__hip_bfloat16 v) { return __bfloat162float(v); }
__device__ __forceinline__ unsigned short f2b(float v) {
    __hip_bfloat16 b = __float2bfloat16(v);
    return *reinterpret_cast<unsigned short*>(&b);
}
__device__ __forceinline__ float u2f(unsigned short u) {
    union { unsigned u; float f; } c; c.u = ((unsigned)u) << 16; return c.f;
}
__device__ __forceinline__ float lrelu01(float v) { return v > 0.f ? v : 0.01f * v; }
__device__ __forceinline__ float lrelu02(float v) { return v > 0.f ? v : 0.2f * v; }

// unpack 2 bf16 from a packed uint: low half = shift, high half = AND
__device__ __forceinline__ void up2(unsigned u, float& lo, float& hi) {
    union { unsigned x; float f; } a, b;
    a.x = u << 16; b.x = u & 0xFFFF0000u;
    lo = a.f; hi = b.f;
}
// acc[0..7] += e * bf16x8(u)
__device__ __forceinline__ void acc8(float* acc, uint4 u, float e) {
    float lo, hi;
    up2(u.x, lo, hi); acc[0] = fmaf(lo, e, acc[0]); acc[1] = fmaf(hi, e, acc[1]);
    up2(u.y, lo, hi); acc[2] = fmaf(lo, e, acc[2]); acc[3] = fmaf(hi, e, acc[3]);
    up2(u.z, lo, hi); acc[4] = fmaf(lo, e, acc[4]); acc[5] = fmaf(hi, e, acc[5]);
    up2(u.w, lo, hi); acc[6] = fmaf(lo, e, acc[6]); acc[7] = fmaf(hi, e, acc[7]);
}
__device__ __forceinline__ unsigned packbf2(float lo, float hi) {
    return ((unsigned)f2b(hi) << 16) | (unsigned)f2b(lo);
}

__device__ __forceinline__ void edge_sd(const int* __restrict__ ei, int e, int& s, int& d) {
    if (e < EE) { s = ei[e]; d = ei[EE + e]; }
    else        { s = e - EE; d = e - EE; }      // self-loop
}

__device__ __forceinline__ float ldf(const void* p, int i, bool bf) {
    return bf ? bf2f(((const __hip_bfloat16*)p)[i]) : ((const float*)p)[i];
}

#define NSEG 20
#define WTOT 85578
#define XQUADS (NN * 32)
// prep index space: EDGES FIRST (rank atomics overlap with convert work) | x quads |
// weights | W1t | W2t | Wgt
#define PREP_TOT (NE2 + XQUADS + WTOT + 32768 + 32768 + 8192)
struct SegArgs { const void* src[NSEG]; int off[NSEG]; };

// fused: per-block dtype detect + edge rank/degree + x->bf16 + fp32 weights + B^T transposes
__global__ __launch_bounds__(256) void prep_k(SegArgs a,
                                              const void* __restrict__ x_raw,
                                              ushort4* __restrict__ xb4,
                                              const void* __restrict__ W1r,
                                              const void* __restrict__ W2r,
                                              const void* __restrict__ Wgr,
                                              float* __restrict__ wf,
                                              unsigned short* __restrict__ W1t,
                                              unsigned short* __restrict__ W2t,
                                              unsigned short* __restrict__ Wgt,
                                              const int* __restrict__ ei,
                                              int* __restrict__ degi,
                                              int* __restrict__ rank,
                                              int* __restrict__ flag) {
    __shared__ int cnt;
    int t = threadIdx.x;
    if (t == 0) cnt = 0;
    __syncthreads();
    {
        int c = 0;
        const unsigned* xw = (const unsigned*)x_raw;
#pragma unroll
        for (int k = 0; k < 4; ++k) {
            unsigned w = xw[t * 4 + k];
            unsigned ef = (w >> 7) & 0xFFu;
            if (ef >= 100u && ef <= 140u) c++;
        }
        atomicAdd(&cnt, c);
    }
    __syncthreads();
    bool bf = (cnt > 512);
    if (blockIdx.x == 0 && t == 0) *flag = bf ? 1 : 0;

    int i = blockIdx.x * 256 + t;
    if (i >= PREP_TOT) return;
    if (i < NE2) {             // edge rank + degree count (degi pre-zeroed by memset)
        int s, d; edge_sd(ei, i, s, d);
        rank[i] = atomicAdd(&degi[d], 1);
        return;
    }
    i -= NE2;
    if (i < XQUADS) {
        ushort4 o;
        if (bf) o = ((const ushort4*)x_raw)[i];
        else {
            float4 v = ((const float4*)x_raw)[i];
            o.x = f2b(v.x); o.y = f2b(v.y); o.z = f2b(v.z); o.w = f2b(v.w);
        }
        xb4[i] = o;
        return;
    }
    i -= XQUADS;
    if (i < WTOT) {
        int s = 0;
#pragma unroll
        for (int k = 1; k < NSEG; ++k) if (i >= a.off[k]) s = k;
        wf[i] = ldf(a.src[s], i - a.off[s], bf);
        return;
    }
    i -= WTOT;
    if (i < 32768) {           // W1 [128][256] -> W1t[n*128+k]
        int n = i >> 7, k = i & 127;
        W1t[i] = f2b(ldf(W1r, k * 256 + n, bf));
        return;
    }
    i -= 32768;
    if (i < 32768) {           // W2 [256][128] -> W2t[n*256+k]
        int n = i >> 8, k = i & 255;
        W2t[i] = f2b(ldf(W2r, k * 128 + n, bf));
        return;
    }
    i -= 32768;
    {                          // Wg [128][64] -> Wgt[n*128+k]
        int n = i >> 7, k = i & 127;
        Wgt[i] = f2b(ldf(Wgr, k * 64 + n, bf));
    }
}

// ---------------- CSR scan phases ----------------
__global__ __launch_bounds__(256) void pscan_k(const int* __restrict__ degi,
                                               int* __restrict__ incl, int* __restrict__ bsum) {
    __shared__ int tmp[256];
    int t = threadIdx.x;
    int i = blockIdx.x * 256 + t;
    int v = (i < NN) ? degi[i] : 0;
    tmp[t] = v;
    __syncthreads();
#pragma unroll
    for (int off = 1; off < 256; off <<= 1) {
        int u = (t >= off) ? tmp[t - off] : 0;
        __syncthreads();
        tmp[t] += u;
        __syncthreads();
    }
    if (i < NN) incl[i] = tmp[t];
    if (t == 255) bsum[blockIdx.x] = tmp[255];
}

// phase 2: exclusive row_ptr + dis + graph bounds; folds the block-sum prefix
// (each block reduces bsum[t < blockIdx] itself -- replaces the bscan launch)
__global__ __launch_bounds__(256) void fscan_k(const int* __restrict__ degi,
                                               const int* __restrict__ incl,
                                               const int* __restrict__ bsum,
                                               const int* __restrict__ batch,
                                               int* __restrict__ row_ptr,
                                               float* __restrict__ dis, int* __restrict__ gstart) {
    __shared__ int tmp[256];
    int t = threadIdx.x, b = blockIdx.x;
    int i = b * 256 + t;
    int x = (t < NSB && t < b) ? bsum[t] : 0;
    tmp[t] = x;
    __syncthreads();
#pragma unroll
    for (int off = 128; off > 0; off >>= 1) {
        if (t < off) tmp[t] += tmp[t + off];
        __syncthreads();
    }
    int base = tmp[0];
    if (i <= NB) {
        int lo = 0, hi = NN;
        while (lo < hi) { int mid = (lo + hi) >> 1; if (batch[mid] < i) lo = mid + 1; else hi = mid; }
        gstart[i] = lo;
    }
    if (i >= NN) return;
    int dg = degi[i];
    int ex = base + incl[i] - dg;
    row_ptr[i] = ex;
    dis[i] = dg > 0 ? rsqrtf((float)dg) : 0.f;
    if (i == NN - 1) row_ptr[NN] = ex + dg;
}

// atomic-free scatter: pos = row_ptr[d] + rank[e] (rank computed in prep_k)
__global__ __launch_bounds__(256) void scatter_k(const int* __restrict__ ei,
                                                 const int* __restrict__ row_ptr,
                                                 const int* __restrict__ rank,
                                                 int* __restrict__ csr_src) {
    int e = blockIdx.x * 256 + threadIdx.x;
    if (e >= NE2) return;
    int s, d; edge_sd(ei, e, s, d);
    csr_src[row_ptr[d] + rank[e]] = s;
}

// ---------------- GEMM1 + fused GAT1 scores: 4 row-tiles/block, B held in regs --------
__global__ __launch_bounds__(256) void mgemm1_k(const short* __restrict__ A,    // xb [N][128]
                                                const short* __restrict__ Bt,   // W1t [256][128]
                                                unsigned short* __restrict__ C, // h1b [N][256]
                                                const float* __restrict__ a_s,  // [256]
                                                const float* __restrict__ a_d,
                                                float* __restrict__ sc_s,       // [N*4]
                                                float* __restrict__ sc_d) {
    int wave = threadIdx.x >> 6, lane = threadIdx.x & 63;
    int cg = wave;
    int l15 = lane & 15, quad = lane >> 4;
    const short* bp = Bt + (size_t)(cg * 64 + l15) * 128 + quad * 8;
    short8 bfr[4][4];
#pragma unroll
    for (int j = 0; j < 4; ++j)
#pragma unroll
        for (int kk = 0; kk < 4; ++kk)
            bfr[j][kk] = *(const short8*)(bp + (size_t)j * 16 * 128 + kk * 32);
    float asv[4], adv[4];
#pragma unroll
    for (int j = 0; j < 4; ++j) {
        asv[j] = a_s[cg * 64 + j * 16 + l15];
        adv[j] = a_d[cg * 64 + j * 16 + l15];
    }
#pragma unroll
    for (int rtl = 0; rtl < 4; ++rtl) {
        int rt = blockIdx.x * 4 + rtl;
        if (rt >= NRT) break;
        const short* ap = A + (size_t)(rt * 16 + l15) * 128 + quad * 8;
        f32x4 acc[4] = {};
#pragma unroll
        for (int kk = 0; kk < 4; ++kk) {
            short8 a = *(const short8*)(ap + kk * 32);
#pragma unroll
            for (int j = 0; j < 4; ++j)
                acc[j] = __builtin_amdgcn_mfma_f32_16x16x32_bf16(a, bfr[j][kk], acc[j], 0, 0, 0);
        }
        float ss[4] = {0.f, 0.f, 0.f, 0.f}, sd[4] = {0.f, 0.f, 0.f, 0.f};
#pragma unroll
        for (int j = 0; j < 4; ++j) {
            int n = cg * 64 + j * 16 + l15;
#pragma unroll
            for (int r = 0; r < 4; ++r) {
                float v = acc[j][r];
                C[(size_t)(rt * 16 + quad * 4 + r) * 256 + n] = f2b(v);
                ss[r] = fmaf(v, asv[j], ss[r]);
                sd[r] = fmaf(v, adv[j], sd[r]);
            }
        }
#pragma unroll
        for (int off = 1; off < 16; off <<= 1) {
#pragma unroll
            for (int r = 0; r < 4; ++r) {
                ss[r] += __shfl_xor(ss[r], off);
                sd[r] += __shfl_xor(sd[r], off);
            }
        }
        if (l15 == 0) {
#pragma unroll
            for (int r = 0; r < 4; ++r) {
                int node = rt * 16 + quad * 4 + r;
                sc_s[node * 4 + cg] = ss[r];
                sc_d[node * 4 + cg] = sd[r];
            }
        }
    }
}

// ---------------- GEMM2 + fused GAT2 scores ----------------
__global__ __launch_bounds__(256) void mgemm2_k(const short* __restrict__ A,    // x1b [N][256]
                                                const short* __restrict__ Bt,   // W2t [128][256]
                                                unsigned short* __restrict__ C, // h2b [N][128]
                                                const float* __restrict__ a_s,  // [128]
                                                const float* __restrict__ a_d,
                                                float* __restrict__ sc_s,       // [N]
                                                float* __restrict__ sc_d) {
    __shared__ float sred[4][16][2];
    int wave = threadIdx.x >> 6, lane = threadIdx.x & 63;
    int gidx = blockIdx.x * 4 + wave;
    bool act = gidx < NRT * 2;
    int gcl = act ? gidx : NRT * 2 - 1;
    int rt = gcl >> 1, cg = gcl & 1;
    int l15 = lane & 15, quad = lane >> 4;
    const short* ap = A + (size_t)(rt * 16 + l15) * 256 + quad * 8;
    const short* bp = Bt + (size_t)(cg * 64 + l15) * 256 + quad * 8;
    f32x4 acc[4] = {};
    for (int k0 = 0; k0 < 256; k0 += 32) {
        short8 a = *(const short8*)(ap + k0);
#pragma unroll
        for (int j = 0; j < 4; ++j) {
            short8 b = *(const short8*)(bp + (size_t)j * 16 * 256 + k0);
            acc[j] = __builtin_amdgcn_mfma_f32_16x16x32_bf16(a, b, acc[j], 0, 0, 0);
        }
    }
    float asv[4], adv[4];
#pragma unroll
    for (int j = 0; j < 4; ++j) {
        asv[j] = a_s[cg * 64 + j * 16 + l15];
        adv[j] = a_d[cg * 64 + j * 16 + l15];
    }
    float ss[4] = {0.f, 0.f, 0.f, 0.f}, sd[4] = {0.f, 0.f, 0.f, 0.f};
#pragma unroll
    for (int j = 0; j < 4; ++j) {
        int n = cg * 64 + j * 16 + l15;
#pragma unroll
        for (int r = 0; r < 4; ++r) {
            float v = acc[j][r];
            if (act) C[(size_t)(rt * 16 + quad * 4 + r) * 128 + n] = f2b(v);
            ss[r] = fmaf(v, asv[j], ss[r]);
            sd[r] = fmaf(v, adv[j], sd[r]);
        }
    }
#pragma unroll
    for (int off = 1; off < 16; off <<= 1) {
#pragma unroll
        for (int r = 0; r < 4; ++r) {
            ss[r] += __shfl_xor(ss[r], off);
            sd[r] += __shfl_xor(sd[r], off);
        }
    }
    if (l15 == 0) {
#pragma unroll
        for (int r = 0; r < 4; ++r) {
            sred[wave][quad * 4 + r][0] = ss[r];
            sred[wave][quad * 4 + r][1] = sd[r];
        }
    }
    __syncthreads();
    if (threadIdx.x < 32) {
        int rl = threadIdx.x >> 4, row = threadIdx.x & 15;
        int g2 = blockIdx.x * 4 + rl * 2;
        if (g2 < NRT * 2) {
            int node = (g2 >> 1) * 16 + row;
            sc_s[node] = sred[rl * 2][row][0] + sred[rl * 2 + 1][row][0];
            sc_d[node] = sred[rl * 2][row][1] + sred[rl * 2 + 1][row][1];
        }
    }
}

// ---------------- GEMM3 (plain): hg = x2 @ Wg; 4 tiles/wave, B held in regs ------------
__global__ __launch_bounds__(256) void mgemm3_k(const short* __restrict__ A,    // x2b [N][128]
                                                const short* __restrict__ Bt,   // Wgt [64][128]
                                                unsigned short* __restrict__ C) {
    int wave = threadIdx.x >> 6, lane = threadIdx.x & 63;
    int wt = blockIdx.x * 4 + wave;
    int l15 = lane & 15, quad = lane >> 4;
    const short* bp = Bt + (size_t)l15 * 128 + quad * 8;
    short8 bfr[4][4];
#pragma unroll
    for (int j = 0; j < 4; ++j)
#pragma unroll
        for (int kk = 0; kk < 4; ++kk)
            bfr[j][kk] = *(const short8*)(bp + (size_t)j * 16 * 128 + kk * 32);
#pragma unroll
    for (int rtl = 0; rtl < 4; ++rtl) {
        int rt = wt * 4 + rtl;
        if (rt >= NRT) break;
        const short* ap = A + (size_t)(rt * 16 + l15) * 128 + quad * 8;
        f32x4 acc[4] = {};
#pragma unroll
        for (int kk = 0; kk < 4; ++kk) {
            short8 a = *(const short8*)(ap + kk * 32);
#pragma unroll
            for (int j = 0; j < 4; ++j)
                acc[j] = __builtin_amdgcn_mfma_f32_16x16x32_bf16(a, bfr[j][kk], acc[j], 0, 0, 0);
        }
#pragma unroll
        for (int j = 0; j < 4; ++j) {
            int n = j * 16 + l15;
#pragma unroll
            for (int r = 0; r < 4; ++r)
                C[(size_t)(rt * 16 + quad * 4 + r) * 64 + n] = f2b(acc[j][r]);
        }
    }
}

__device__ __forceinline__ float sel4(float4 v, int head) {
    float ab = (head & 1) ? v.y : v.x;
    float cd = (head & 1) ? v.w : v.z;
    return (head & 2) ? cd : ab;
}

// ---------------- GAT1 aggregate: wave/node, 4B L2 score gathers, masked tail ----------
__global__ __launch_bounds__(256) void agg1_k(const int* __restrict__ row_ptr,
                                              const int* __restrict__ csr_src,
                                              const uint4* __restrict__ h1b,    // [N*32]
                                              const float* __restrict__ sc_s,   // [N*4]
                                              const float4* __restrict__ sc_d4, // [N]
                                              const float4* __restrict__ b1,    // [64]
                                              const float4* __restrict__ g1,
                                              const float4* __restrict__ bb1,
                                              uint4* __restrict__ x1b) {
    int n = __builtin_amdgcn_readfirstlane((blockIdx.x * 256 + threadIdx.x) >> 6);
    int lane = threadIdx.x & 63;
    if (n >= NN) return;
    int g = lane >> 5, sl = lane & 31;
    int head = sl >> 3;
    int row = row_ptr[n], end = row_ptr[n + 1];
    float scd_h = sel4(sc_d4[n], head);
    float acc[8] = {0.f, 0.f, 0.f, 0.f, 0.f, 0.f, 0.f, 0.f};
    float den = 0.f;
    int c = row;
    for (; c + 7 < end; c += 8) {
        int i0 = c + g, i1 = c + 2 + g, i2 = c + 4 + g, i3 = c + 6 + g;
        int s0 = csr_src[i0], s1 = csr_src[i1], s2 = csr_src[i2], s3 = csr_src[i3];
        float w0 = sc_s[s0 * 4 + head], w1 = sc_s[s1 * 4 + head];
        float w2 = sc_s[s2 * 4 + head], w3 = sc_s[s3 * 4 + head];
        uint4 u0 = h1b[(size_t)s0 * 32 + sl];
        uint4 u1 = h1b[(size_t)s1 * 32 + sl];
        uint4 u2 = h1b[(size_t)s2 * 32 + sl];
        uint4 u3 = h1b[(size_t)s3 * 32 + sl];
        float e0 = __expf(lrelu02(w0 + scd_h));
        float e1 = __expf(lrelu02(w1 + scd_h));
        float e2 = __expf(lrelu02(w2 + scd_h));
        float e3 = __expf(lrelu02(w3 + scd_h));
        den += (e0 + e1) + (e2 + e3);
        acc8(acc, u0, e0); acc8(acc, u1, e1); acc8(acc, u2, e2); acc8(acc, u3, e3);
    }
    if (c < end) {                               // masked full-width tail (<=7 edges)
        int i0 = c + g, i1 = c + 2 + g, i2 = c + 4 + g, i3 = c + 6 + g;
        bool v0 = i0 < end, v1 = i1 < end, v2 = i2 < end, v3 = i3 < end;
        int l = end - 1;
        int s0 = csr_src[v0 ? i0 : l], s1 = csr_src[v1 ? i1 : l];
        int s2 = csr_src[v2 ? i2 : l], s3 = csr_src[v3 ? i3 : l];
        float w0 = sc_s[s0 * 4 + head], w1 = sc_s[s1 * 4 + head];
        float w2 = sc_s[s2 * 4 + head], w3 = sc_s[s3 * 4 + head];
        uint4 u0 = h1b[(size_t)s0 * 32 + sl];
        uint4 u1 = h1b[(size_t)s1 * 32 + sl];
        uint4 u2 = h1b[(size_t)s2 * 32 + sl];
        uint4 u3 = h1b[(size_t)s3 * 32 + sl];
        float e0 = v0 ? __expf(lrelu02(w0 + scd_h)) : 0.f;
        float e1 = v1 ? __expf(lrelu02(w1 + scd_h)) : 0.f;
        float e2 = v2 ? __expf(lrelu02(w2 + scd_h)) : 0.f;
        float e3 = v3 ? __expf(lrelu02(w3 + scd_h)) : 0.f;
        den += (e0 + e1) + (e2 + e3);
        acc8(acc, u0, e0); acc8(acc, u1, e1); acc8(acc, u2, e2); acc8(acc, u3, e3);
    }
    den += __shfl_xor(den, 32);
#pragma unroll
    for (int k = 0; k < 8; ++k) acc[k] += __shfl_xor(acc[k], 32);
    if (g == 0) {
        float inv = 1.f / (den + 1e-16f);
        float4 bA = b1[sl * 2],  bB = b1[sl * 2 + 1];
        float4 gA = g1[sl * 2],  gB = g1[sl * 2 + 1];
        float4 eA = bb1[sl * 2], eB = bb1[sl * 2 + 1];
        float o0 = lrelu01(fmaf(acc[0], inv, bA.x)) * (gA.x * BN_RS) + eA.x;
        float o1 = lrelu01(fmaf(acc[1], inv, bA.y)) * (gA.y * BN_RS) + eA.y;
        float o2 = lrelu01(fmaf(acc[2], inv, bA.z)) * (gA.z * BN_RS) + eA.z;
        float o3 = lrelu01(fmaf(acc[3], inv, bA.w)) * (gA.w * BN_RS) + eA.w;
        float o4 = lrelu01(fmaf(acc[4], inv, bB.x)) * (gB.x * BN_RS) + eB.x;
        float o5 = lrelu01(fmaf(acc[5], inv, bB.y)) * (gB.y * BN_RS) + eB.y;
        float o6 = lrelu01(fmaf(acc[6], inv, bB.z)) * (gB.z * BN_RS) + eB.z;
        float o7 = lrelu01(fmaf(acc[7], inv, bB.w)) * (gB.w * BN_RS) + eB.w;
        uint4 w;
        w.x = packbf2(o0, o1); w.y = packbf2(o2, o3);
        w.z = packbf2(o4, o5); w.w = packbf2(o6, o7);
        x1b[(size_t)n * 32 + sl] = w;
    }
}

// ---------------- GAT2 aggregate: 4 edge-groups x 16 lanes, masked tail ----------------
__global__ __launch_bounds__(256) void agg2_k(const int* __restrict__ row_ptr,
                                              const int* __restrict__ csr_src,
                                              const uint4* __restrict__ h2b,   // [N*16]
                                              const float* __restrict__ sc_s,  // [N]
                                              const float* __restrict__ sc_d,
                                              const float4* __restrict__ b2,   // [32]
                                              const float4* __restrict__ g2,
                                              const float4* __restrict__ bb2,
                                              uint4* __restrict__ x2b) {
    int n = __builtin_amdgcn_readfirstlane((blockIdx.x * 256 + threadIdx.x) >> 6);
    int lane = threadIdx.x & 63;
    if (n >= NN) return;
    int g = lane >> 4, sl = lane & 15;
    int row = row_ptr[n], end = row_ptr[n + 1];
    float scd = sc_d[n];
    float acc[8] = {0.f, 0.f, 0.f, 0.f, 0.f, 0.f, 0.f, 0.f};
    float den = 0.f;
    int c = row;
    for (; c + 15 < end; c += 16) {              // 4 slots/group, 16 edges/wave
        int i0 = c + g, i1 = c + 4 + g, i2 = c + 8 + g, i3 = c + 12 + g;
        int s0 = csr_src[i0], s1 = csr_src[i1], s2 = csr_src[i2], s3 = csr_src[i3];
        float c0 = sc_s[s0], c1 = sc_s[s1], c2 = sc_s[s2], c3 = sc_s[s3];
        uint4 u0 = h2b[(size_t)s0 * 16 + sl];
        uint4 u1 = h2b[(size_t)s1 * 16 + sl];
        uint4 u2 = h2b[(size_t)s2 * 16 + sl];
        uint4 u3 = h2b[(size_t)s3 * 16 + sl];
        float e0 = __expf(lrelu02(c0 + scd));
        float e1 = __expf(lrelu02(c1 + scd));
        float e2 = __expf(lrelu02(c2 + scd));
        float e3 = __expf(lrelu02(c3 + scd));
        den += (e0 + e1) + (e2 + e3);
        acc8(acc, u0, e0); acc8(acc, u1, e1); acc8(acc, u2, e2); acc8(acc, u3, e3);
    }
    if (c < end) {                               // masked full-width tail (<=15 edges)
        int i0 = c + g, i1 = c + 4 + g, i2 = c + 8 + g, i3 = c + 12 + g;
        bool v0 = i0 < end, v1 = i1 < end, v2 = i2 < end, v3 = i3 < end;
        int l = end - 1;
        int s0 = csr_src[v0 ? i0 : l], s1 = csr_src[v1 ? i1 : l];
        int s2 = csr_src[v2 ? i2 : l], s3 = csr_src[v3 ? i3 : l];
        float c0 = sc_s[s0], c1 = sc_s[s1], c2 = sc_s[s2], c3 = sc_s[s3];
        uint4 u0 = h2b[(size_t)s0 * 16 + sl];
        uint4 u1 = h2b[(size_t)s1 * 16 + sl];
        uint4 u2 = h2b[(size_t)s2 * 16 + sl];
        uint4 u3 = h2b[(size_t)s3 * 16 + sl];
        float e0 = v0 ? __expf(lrelu02(c0 + scd)) : 0.f;
        float e1 = v1 ? __expf(lrelu02(c1 + scd)) : 0.f;
        float e2 = v2 ? __expf(lrelu02(c2 + scd)) : 0.f;
        float e3 = v3 ? __expf(lrelu02(c3 + scd)) : 0.f;
        den += (e0 + e1) + (e2 + e3);
        acc8(acc, u0, e0); acc8(acc, u1, e1); acc8(acc, u2, e2); acc8(acc, u3, e3);
    }
    den += __shfl_xor(den, 16);
    den += __shfl_xor(den, 32);
#pragma unroll
    for (int k = 0; k < 8; ++k) {
        acc[k] += __shfl_xor(acc[k], 16);
        acc[k] += __shfl_xor(acc[k], 32);
    }
    if (lane < 16) {
        float inv = 1.f / (den + 1e-16f);
        float4 bA = b2[sl * 2],  bB = b2[sl * 2 + 1];
        float4 gA = g2[sl * 2],  gB = g2[sl * 2 + 1];
        float4 eA = bb2[sl * 2], eB = bb2[sl * 2 + 1];
        float o0 = lrelu01(fmaf(acc[0], inv, bA.x)) * (gA.x * BN_RS) + eA.x;
        float o1 = lrelu01(fmaf(acc[1], inv, bA.y)) * (gA.y * BN_RS) + eA.y;
        float o2 = lrelu01(fmaf(acc[2], inv, bA.z)) * (gA.z * BN_RS) + eA.z;
        float o3 = lrelu01(fmaf(acc[3], inv, bA.w)) * (gA.w * BN_RS) + eA.w;
        float o4 = lrelu01(fmaf(acc[4], inv, bB.x)) * (gB.x * BN_RS) + eB.x;
        float o5 = lrelu01(fmaf(acc[5], inv, bB.y)) * (gB.y * BN_RS) + eB.y;
        float o6 = lrelu01(fmaf(acc[6], inv, bB.z)) * (gB.z * BN_RS) + eB.z;
        float o7 = lrelu01(fmaf(acc[7], inv, bB.w)) * (gB.w * BN_RS) + eB.w;
        uint4 w;
        w.x = packbf2(o0, o1); w.y = packbf2(o2, o3);
        w.z = packbf2(o4, o5); w.w = packbf2(o6, o7);
        x2b[(size_t)n * 16 + sl] = w;
    }
}

// ---------------- GCN aggregate: 8 edge-groups x 8 lanes, masked tail; bf16 x3 ---------
__global__ __launch_bounds__(256) void gcn_k(const int* __restrict__ row_ptr,
                                             const int* __restrict__ csr_src,
                                             const uint4* __restrict__ hgb,  // [N*8]
                                             const float* __restrict__ dis,
                                             const float4* __restrict__ bg,  // [16]
                                             uint4* __restrict__ x3b) {      // [N*8] bf16
    int n = __builtin_amdgcn_readfirstlane((blockIdx.x * 256 + threadIdx.x) >> 6);
    int lane = threadIdx.x & 63;
    if (n >= NN) return;
    int g = lane >> 3, sl = lane & 7;
    int row = row_ptr[n], end = row_ptr[n + 1];
    float dn = dis[n];
    float acc[8] = {0.f, 0.f, 0.f, 0.f, 0.f, 0.f, 0.f, 0.f};
    int c = row;
    for (; c + 15 < end; c += 16) {              // 2 slots/group, 16 edges/wave
        int i0 = c + g, i1 = c + 8 + g;
        int s0 = csr_src[i0], s1 = csr_src[i1];
        float w0 = dis[s0], w1 = dis[s1];
        uint4 u0 = hgb[(size_t)s0 * 8 + sl];
        uint4 u1 = hgb[(size_t)s1 * 8 + sl];
        acc8(acc, u0, w0); acc8(acc, u1, w1);
    }
    if (c < end) {                               // masked full-width tail (<=15 edges)
        int i0 = c + g, i1 = c + 8 + g;
        bool v0 = i0 < end, v1 = i1 < end;
        int l = end - 1;
        int s0 = csr_src[v0 ? i0 : l], s1 = csr_src[v1 ? i1 : l];
        float w0 = v0 ? dis[s0] : 0.f, w1 = v1 ? dis[s1] : 0.f;
        uint4 u0 = hgb[(size_t)s0 * 8 + sl];
        uint4 u1 = hgb[(size_t)s1 * 8 + sl];
        acc8(acc, u0, w0); acc8(acc, u1, w1);
    }
#pragma unroll
    for (int off = 8; off <= 32; off <<= 1) {
#pragma unroll
        for (int k = 0; k < 8; ++k) acc[k] += __shfl_xor(acc[k], off);
    }
    if (lane < 8) {
        float4 bA = bg[sl * 2], bB = bg[sl * 2 + 1];
        float o0 = lrelu01(fmaf(acc[0], dn, bA.x));
        float o1 = lrelu01(fmaf(acc[1], dn, bA.y));
        float o2 = lrelu01(fmaf(acc[2], dn, bA.z));
        float o3 = lrelu01(fmaf(acc[3], dn, bA.w));
        float o4 = lrelu01(fmaf(acc[4], dn, bB.x));
        float o5 = lrelu01(fmaf(acc[5], dn, bB.y));
        float o6 = lrelu01(fmaf(acc[6], dn, bB.z));
        float o7 = lrelu01(fmaf(acc[7], dn, bB.w));
        uint4 w;
        w.x = packbf2(o0, o1); w.y = packbf2(o2, o3);
        w.z = packbf2(o4, o5); w.w = packbf2(o6, o7);
        x3b[(size_t)n * 8 + sl] = w;
    }
}

// ---------------- fused mean-pool + MLP head: block per graph (bf16 x3) ----------------
__global__ __launch_bounds__(256) void poolmlp_k(const unsigned short* __restrict__ x3b,
                                                 const int* __restrict__ gstart,
                                                 const float* __restrict__ l1W,
                                                 const float* __restrict__ l1b,
                                                 const float* __restrict__ g3,
                                                 const float* __restrict__ b3,
                                                 const float* __restrict__ l2W,
                                                 const float* __restrict__ l2b,
                                                 void* __restrict__ outp,
                                                 const int* __restrict__ flag) {
    __shared__ float red[4][64];
    __shared__ float pl[64];
    __shared__ float y1s[128];
    int g = blockIdx.x, t = threadIdx.x;
    int c = t & 63, r = t >> 6;
    int s = gstart[g], e = gstart[g + 1];
    float sum = 0.f;
    for (int n = s + r; n < e; n += 4) sum += u2f(x3b[(size_t)n * 64 + c]);
    red[r][c] = sum;
    __syncthreads();
    if (t < 64) {
        float v = red[0][t] + red[1][t] + red[2][t] + red[3][t];
        int cnt = e - s; if (cnt < 1) cnt = 1;
        pl[t] = v / (float)cnt;
    }
    __syncthreads();
    if (t < 128) {
        float acc = l1b[t];
#pragma unroll 8
        for (int j = 0; j < 64; ++j) acc = fmaf(pl[j], l1W[j * 128 + t], acc);
        acc = acc * (g3[t] * BN_RS) + b3[t];
        y1s[t] = lrelu01(acc);
    }
    __syncthreads();
    if (t < 10) {
        float o = l2b[t];
#pragma unroll 8
        for (int j = 0; j < 128; ++j) o = fmaf(y1s[j], l2W[j * 10 + t], o);
        if (*flag) ((__hip_bfloat16*)outp)[g * 10 + t] = __float2bfloat16(o);
        else       ((float*)outp)[g * 10 + t] = o;
    }
}

// weight segment sizes (W1,as1,ad1,b1,W2,as2,ad2,b2,Wg,bg,bn1g,bn1b,bn2g,bn2b,bn3g,bn3b,l1W,l1b,l2W,l2b)
static const int kSegN[NSEG]  = {32768, 256, 256, 256, 32768, 128, 128, 128, 8192, 64,
                                 256, 256, 128, 128, 128, 128, 8192, 128, 1280, 10};
static const int kSegIn[NSEG] = {3, 4, 5, 6, 7, 8, 9, 10, 11, 12, 13, 14, 15, 16, 17, 18, 19, 20, 21, 22};

extern "C" void kernel_launch(void* const* d_in, const int* in_sizes, int n_in,
                              void* d_out, int out_size, void* d_ws, size_t ws_size,
                              hipStream_t stream) {
    const void* x_raw = d_in[0];
    const int*  ei    = (const int*)d_in[1];
    const int*  batch = (const int*)d_in[2];

    // ---- workspace layout ----
    int*   flag = (int*)d_ws;
    float* ws   = (float*)d_ws;
    unsigned short* xb = (unsigned short*)(ws + 16);          // N*128 bf16
    float* wf   = ws + 16 + (size_t)NN * 64;                  // 85584 fp32 canonical
    unsigned short* W1t = (unsigned short*)(wf + 85584);      // 32768 bf16 [256][128]
    unsigned short* W2t = W1t + 32768;                        // 32768 bf16 [128][256]
    unsigned short* Wgt = W2t + 32768;                        // 8192  bf16 [64][128]
    unsigned short* h1b = Wgt + 8192;                         // N*256 bf16 (reused as h2b)
    unsigned short* x1b = h1b + (size_t)NN * 256;             // N*256 bf16
    unsigned short* x2b = x1b + (size_t)NN * 256;             // N*128 bf16
    unsigned short* hgb = x2b + (size_t)NN * 128;             // N*64 bf16
    unsigned short* x3b = hgb + (size_t)NN * 64;              // N*64 bf16
    float* sc_s1 = (float*)(x3b + (size_t)NN * 64);           // N*4
    float* sc_d1 = sc_s1 + (size_t)NN * 4;                    // N*4
    float* sc_s2 = sc_d1 + (size_t)NN * 4;                    // N
    float* sc_d2 = sc_s2 + NN;                                // N
    float* disb  = sc_d2 + NN;                                // N
    int*   gstart = (int*)(disb + NN);                        // B+1
    int*   degi   = gstart + NB + 4;                          // N
    int*   incl   = degi + NN;                                // N
    int*   bsum   = incl + NN;                                // 256
    int*   row_ptr = bsum + 256;                              // N+1
    int*   csr_src = row_ptr + NN + 4;                        // NE2

    // rank[e]: within-destination edge rank, produced by prep_k, consumed by scatter_k.
    // Aliases x1b region (first written by agg1_k, which runs after scatter_k).
    int*   rankb = (int*)x1b;                                 // NE2 ints (3.4MB of 25.6MB)

    int off[NSEG]; int o = 0;
    for (int s = 0; s < NSEG; ++s) { off[s] = o; o += kSegN[s]; }
    float* as1f = wf + off[1];  float* ad1f = wf + off[2];
    float* b1f  = wf + off[3];  float* as2f = wf + off[5];
    float* ad2f = wf + off[6];  float* b2f  = wf + off[7];
    float* bgf  = wf + off[9];  float* bn1g = wf + off[10]; float* bn1b = wf + off[11];
    float* bn2g = wf + off[12]; float* bn2b = wf + off[13]; float* bn3g = wf + off[14];
    float* bn3b = wf + off[15]; float* l1Wf = wf + off[16]; float* l1bf = wf + off[17];
    float* l2Wf = wf + off[18]; float* l2bf = wf + off[19];

    unsigned short* h2b = h1b;   // h1b dead after agg1_k

    // ---- prep: degi zero (memset) + edge rank + detect/convert/transpose (one kernel) ----
    hipMemsetAsync(degi, 0, NN * sizeof(int), stream);
    SegArgs sa;
    for (int s = 0; s < NSEG; ++s) { sa.src[s] = d_in[kSegIn[s]]; sa.off[s] = off[s]; }
    prep_k<<<(PREP_TOT + 255) / 256, 256, 0, stream>>>(sa, x_raw, (ushort4*)xb,
                                                       d_in[3], d_in[7], d_in[11],
                                                       wf, W1t, W2t, Wgt, ei, degi, rankb, flag);

    // ---- CSR build (by destination) + graph bounds; bscan folded into fscan ----
    pscan_k<<<NSB, 256, 0, stream>>>(degi, incl, bsum);
    fscan_k<<<NSB, 256, 0, stream>>>(degi, incl, bsum, batch, row_ptr, disb, gstart);
    scatter_k<<<NEB, 256, 0, stream>>>(ei, row_ptr, rankb, csr_src);

    // ---- GAT layer 1 (scores fused into GEMM; 4B L2 score gathers in aggregate) ----
    mgemm1_k<<<(NRT + 3) / 4, 256, 0, stream>>>((const short*)xb, (const short*)W1t, h1b,
                                                as1f, ad1f, sc_s1, sc_d1);
    agg1_k<<<12500, 256, 0, stream>>>(row_ptr, csr_src, (const uint4*)h1b,
                                      sc_s1, (const float4*)sc_d1,
                                      (const float4*)b1f, (const float4*)bn1g,
                                      (const float4*)bn1b, (uint4*)x1b);

    // ---- GAT layer 2 ----
    mgemm2_k<<<(NRT * 2 + 3) / 4, 256, 0, stream>>>((const short*)x1b, (const short*)W2t, h2b,
                                                    as2f, ad2f, sc_s2, sc_d2);
    agg2_k<<<12500, 256, 0, stream>>>(row_ptr, csr_src, (const uint4*)h2b,
                                      sc_s2, sc_d2,
                                      (const float4*)b2f, (const float4*)bn2g,
                                      (const float4*)bn2b, (uint4*)x2b);

    // ---- GCN + fused pool/MLP ----
    mgemm3_k<<<(NRT + 15) / 16, 256, 0, stream>>>((const short*)x2b, (const short*)Wgt, hgb);
    gcn_k<<<12500, 256, 0, stream>>>(row_ptr, csr_src, (const uint4*)hgb, disb,
                                     (const float4*)bgf, (uint4*)x3b);
    poolmlp_k<<<NB, 256, 0, stream>>>(x3b, gstart, l1Wf, l1bf, bn3g, bn3b, l2Wf, l2bf,
                                      d_out, flag);
}